// Round 8
// baseline (1047.702 us; speedup 1.0000x reference)
//
#include <hip/hip_runtime.h>
#include <math.h>

#define EMB 256
#define VOCAB 50000
#define TROWS 101
#define NLB 32    // lstm candidate blocks (election among these; 4 winners)
#define NW 4      // lstm worker workgroups
#define NDECB 782 // decode blocks: 64 vocab rows each (782*64 = 50048 >= 50000)
#define NTOT (NLB + NDECB)

__device__ __forceinline__ float sigf(float x) { return 1.0f / (1.0f + expf(-x)); }

// ---------------------------------------------------------------------------
// Single fused kernel.
// Round-8 decode redesign: rounds 5-7 proved the allocator pins ~84-88 VGPRs
// and REMATERIALIZES any 128-reg weight array (48 MB/step of hidden L2/MALL
// re-reads -> MALL saturation paced everything at ~3.2us/step). Fix: decode
// threads hold only 8 float4 (32 regs) -> pressure ~60 < budget -> truly
// register-resident by construction. 8 thr/row x 32 cols, 64 rows/block.
//
// h hand-off: producer writes tagged u64 {t+1, h} packets (round-0-proven
// self-validating pattern) to full-history hdec[t][j] AND to 8 per-XCD
// parity mirrors (contention split: each mirror polled by ~1/8 of blocks).
// Mirror slot with a LATER valid tag (<=101) implies history is visible
// (producer's per-step __syncthreads drains vmcnt -> cross-step store order),
// so late/tail blocks fall back to one history load. No flags, no release.
// ---------------------------------------------------------------------------
__global__ __launch_bounds__(512) void k_net(
    const float* __restrict__ board, const float* __restrict__ conv_w,
    const float* __restrict__ conv_b, const float* __restrict__ bn_g,
    const float* __restrict__ bn_b, const float* __restrict__ p,
    const float* __restrict__ W_lin, const float* __restrict__ b_lin,
    const float* __restrict__ W_ih, const float* __restrict__ b_ih,
    const float* __restrict__ W_hh, const float* __restrict__ b_hh,
    const float* __restrict__ W_dec, const float* __restrict__ b_dec,
    unsigned long long* hcomm, unsigned long long* xtab,
    unsigned long long* hdec, unsigned long long* hmir,
    float* __restrict__ out) {
  __shared__ float xa[361], xb[361];
  __shared__ float wred[8];
  __shared__ float mu_s, var_s;
  __shared__ float h_lds[EMB];
  __shared__ float gbuf[2][EMB];
  __shared__ float h_stage[2][EMB];
  __shared__ int sxcd[NLB];
  const int tid = threadIdx.x;

  if (blockIdx.x >= NLB) {
    // ======================= decode role =======================
    const int db = blockIdx.x - NLB;      // 0..781
    const int lane = tid & 63;
    const int wv = tid >> 6;
    const int s = tid & 7;                // col group: cols [s*32, s*32+32)
    const int r = tid >> 3;               // row within tile 0..63
    const int v = db * 64 + r;
    const int rv = v < VOCAB ? v : VOCAB - 1;
    const unsigned myx = __builtin_amdgcn_s_getreg(63508) & 7u;  // HW_REG_XCC_ID

    float4 w8[8];                         // 32 weight cols in regs (32 VGPRs)
    {
      const float4* wr = (const float4*)(W_dec + rv * EMB + s * 32);
#pragma unroll
      for (int q = 0; q < 8; q++) w8[q] = wr[q];
    }
    const float bd = b_dec[rv];

    for (int t = 0; t < TROWS; t++) {
      if (wv == 0) {  // wave 0 stages h[t] into LDS (4 slots/lane)
        const unsigned want = (unsigned)(t + 1);
        const unsigned long long* mbase = hmir + ((myx * 2 + (t & 1)) * EMB);
        const unsigned long long* hbase = hdec + t * EMB;
#pragma unroll
        for (int q2 = 0; q2 < 4; q2++) {
          const int j = q2 * 64 + lane;
          unsigned long long u;
          while (1) {
            u = __hip_atomic_load(&mbase[j], __ATOMIC_RELAXED, __HIP_MEMORY_SCOPE_AGENT);
            const unsigned tg = (unsigned)(u >> 32);
            if (tg == want) break;
            if (tg > want && tg <= 101u) {
              // parity slot overwritten by a later step => history(t) is
              // globally visible (producer barriers drain vmcnt each step).
              do {
                u = __hip_atomic_load(&hbase[j], __ATOMIC_RELAXED, __HIP_MEMORY_SCOPE_AGENT);
              } while ((unsigned)(u >> 32) != want);
              break;
            }
            __builtin_amdgcn_s_sleep(4);
          }
          h_stage[t & 1][j] = __uint_as_float((unsigned)u);
        }
      }
      __syncthreads();  // h_stage[t&1] ready (parity dbuf: wave0 may run ahead)

      const float4* hs4 = (const float4*)&h_stage[t & 1][s * 32];
      float a0 = 0.f, a1 = 0.f, a2 = 0.f, a3 = 0.f;
#pragma unroll
      for (int q = 0; q < 8; q++) {
        const float4 hv4 = hs4[q], wvv = w8[q];
        a0 = fmaf(wvv.x, hv4.x, a0);
        a1 = fmaf(wvv.y, hv4.y, a1);
        a2 = fmaf(wvv.z, hv4.z, a2);
        a3 = fmaf(wvv.w, hv4.w, a3);
      }
      float a = (a0 + a1) + (a2 + a3);
      a += __shfl_xor(a, 1);
      a += __shfl_xor(a, 2);
      a += __shfl_xor(a, 4);   // 8-lane row reduce
      if (s == 0 && v < VOCAB) out[t * VOCAB + v] = fmaxf(a + bd, 0.f);
    }
    return;
  }

  // ======================= candidate role =======================
  if (tid == 0) {
    unsigned xcc = __builtin_amdgcn_s_getreg(63508) & 7u;  // HW_REG_XCC_ID
    __hip_atomic_store(&xtab[blockIdx.x],
                       0xE1EC000000000000ULL | (unsigned long long)xcc,
                       __ATOMIC_RELAXED, __HIP_MEMORY_SCOPE_AGENT);
  }

  // ---- conv tower, computed redundantly by every candidate block ----
  {
    const bool act = tid < 361;
    const int ci = tid / 19, cj = tid % 19;
    float cw[9];
#pragma unroll
    for (int q = 0; q < 9; q++) cw[q] = conv_w[q];
    const float cb = conv_b[0], gam = bn_g[0], bet = bn_b[0];
    if (act) xa[tid] = board[tid];
    __syncthreads();

    float d2 = 0.f;
    float* cur = xa;
    float* nxt = xb;
    for (int stage = 0; stage < 8; stage++) {
      float y = 0.f;
      if (act) {
#pragma unroll
        for (int di = 0; di < 3; di++) {
#pragma unroll
          for (int dj = 0; dj < 3; dj++) {
            int ii = ci + di - 1, jj = cj + dj - 1;
            float xv = (ii >= 0 && ii < 19 && jj >= 0 && jj < 19) ? cur[ii * 19 + jj] : 0.f;
            y += cw[di * 3 + dj] * xv;
          }
        }
        y += cb;
      }
      float sacc = act ? y : 0.f;
#pragma unroll
      for (int o = 32; o > 0; o >>= 1) sacc += __shfl_xor(sacc, o);
      if ((tid & 63) == 0) wred[tid >> 6] = sacc;
      __syncthreads();
      if (tid == 0) {
        float tt = 0.f;
        for (int q = 0; q < 8; q++) tt += wred[q];
        mu_s = tt / 361.f;
      }
      __syncthreads();
      const float mu = mu_s;
      float d = act ? (y - mu) : 0.f;
      sacc = d * d;
#pragma unroll
      for (int o = 32; o > 0; o >>= 1) sacc += __shfl_xor(sacc, o);
      if ((tid & 63) == 0) wred[tid >> 6] = sacc;
      __syncthreads();
      if (tid == 0) {
        float tt = 0.f;
        for (int q = 0; q < 8; q++) tt += wred[q];
        var_s = tt / 361.f;
      }
      __syncthreads();
      const float xn = gam * (y - mu) * (1.0f / sqrtf(var_s + 1e-5f)) + bet;

      float vv;
      if (stage == 0) {
        vv = fmaxf(p[0] * xn, 0.f);
        d2 = vv;
      } else if (stage == 7) {
        vv = fmaxf(xn, 0.f);
      } else if (stage & 1) {
        vv = fmaxf(p[stage] * xn, 0.f);
      } else {
        vv = fmaxf(p[stage] * xn + d2, 0.f);
        d2 = vv;
      }
      if (act) nxt[tid] = vv;
      __syncthreads();
      float* tmp = cur; cur = nxt; nxt = tmp;
    }
    // cur == xa holds d1 (361 values) for the feat step below.
  }

  // ---- election (proven machinery) ----
  if (tid < NLB) {
    const unsigned long long* slot = &xtab[tid];
    unsigned long long u;
    while (1) {
      u = __hip_atomic_load(slot, __ATOMIC_RELAXED, __HIP_MEMORY_SCOPE_AGENT);
      if ((unsigned)(u >> 32) == 0xE1EC0000u) break;
      __builtin_amdgcn_s_sleep(2);
    }
    sxcd[tid] = (int)((unsigned)u & 7u);
  }
  __syncthreads();
  int target = -1;
  for (int x = 0; x < 8; x++) {
    int n = 0;
    for (int b = 0; b < NLB; b++) n += (sxcd[b] == x);
    if (n >= NW) { target = x; break; }
  }
  int rank = -1, seen = 0;
  for (int b = 0; b < NLB; b++) {
    if (sxcd[b] == target) {
      if (b == (int)blockIdx.x) rank = seen;
      seen++;
    }
  }
  if (rank < 0 || rank >= NW) return;  // losers exit, free their CUs
  const int g = rank;

  // ---- feat = W_lin @ d1 + b_lin, each winner for itself ----
  {
    const float* d1 = xa;
    const int fr = tid >> 1, fs = tid & 1;
    const float* wrow = W_lin + fr * 361;
    float a0 = 0.f, a1 = 0.f, a2 = 0.f, a3 = 0.f;
    int k = fs;
    for (; k + 6 < 361; k += 8) {
      a0 = fmaf(wrow[k],     d1[k],     a0);
      a1 = fmaf(wrow[k + 2], d1[k + 2], a1);
      a2 = fmaf(wrow[k + 4], d1[k + 4], a2);
      a3 = fmaf(wrow[k + 6], d1[k + 6], a3);
    }
    for (; k < 361; k += 2) a0 = fmaf(wrow[k], d1[k], a0);
    float sred = (a0 + a1) + (a2 + a3);
    sred += __shfl_xor(sred, 1);
    if (fs == 0) h_lds[fr] = sred + b_lin[fr];
  }
  float c = 0.f;

  // ---- LSTM body (proven protocol, unchanged math) ----
  const int w = tid >> 6, lane = tid & 63;
  const int half = w & 1;
  const int gate = w >> 1;
  const int rloc = gate * 64 + lane;
  const int R = gate * 256 + g * 64 + lane;
  const float bsum = b_ih[R] + b_hh[R];

  float4 w4[32];
  {
    const float4* wih = (const float4*)(W_ih + R * EMB + half * 128);
#pragma unroll
    for (int q = 0; q < 32; q++) w4[q] = wih[q];
  }
  __syncthreads();  // h_lds(feat) ready

  for (int t = 0; t <= 100; t++) {
    const float hv0 = h_lds[half * 128 + lane];
    const float hv1 = h_lds[half * 128 + 64 + lane];

    float a0 = (half == 0) ? bsum : 0.f, a1 = 0.f, a2 = 0.f, a3 = 0.f;
#pragma unroll
    for (int k = 0; k < 32; k++) {
      const float4 wv = w4[k];
      const int kk = 4 * k;
      const float s0 = __uint_as_float(__builtin_amdgcn_readlane(
          __float_as_uint(kk + 0 < 64 ? hv0 : hv1), (kk + 0) & 63));
      const float s1 = __uint_as_float(__builtin_amdgcn_readlane(
          __float_as_uint(kk + 1 < 64 ? hv0 : hv1), (kk + 1) & 63));
      const float s2 = __uint_as_float(__builtin_amdgcn_readlane(
          __float_as_uint(kk + 2 < 64 ? hv0 : hv1), (kk + 2) & 63));
      const float s3 = __uint_as_float(__builtin_amdgcn_readlane(
          __float_as_uint(kk + 3 < 64 ? hv0 : hv1), (kk + 3) & 63));
      a0 = fmaf(s0, wv.x, a0);
      a1 = fmaf(s1, wv.y, a1);
      a2 = fmaf(s2, wv.z, a2);
      a3 = fmaf(s3, wv.w, a3);
    }
    gbuf[half][rloc] = (a0 + a1) + (a2 + a3);
    __syncthreads();  // B1: gbuf ready; h_lds reads of this step done

    if (tid < 64) {   // producer wave
      const float gi = gbuf[0][tid]       + gbuf[1][tid];
      const float gf = gbuf[0][64 + tid]  + gbuf[1][64 + tid];
      const float gg = gbuf[0][128 + tid] + gbuf[1][128 + tid];
      const float go = gbuf[0][192 + tid] + gbuf[1][192 + tid];
      c = sigf(gf) * c + sigf(gi) * tanhf(gg);
      const float h = sigf(go) * tanhf(c);
      const int j = g * 64 + tid;
      h_lds[j] = h;  // local fast path
      const unsigned long long pkt =
          ((unsigned long long)(unsigned)(t + 1) << 32) | (unsigned long long)__float_as_uint(h);
      // full-history packet (tail/fallback consumers)
      __hip_atomic_store(&hdec[t * EMB + j], pkt,
                         __ATOMIC_RELAXED, __HIP_MEMORY_SCOPE_AGENT);
      // 8 per-XCD parity mirrors (resident consumers; contention split)
#pragma unroll
      for (int x = 0; x < 8; x++)
        __hip_atomic_store(&hmir[((x * 2 + (t & 1)) * EMB) + j], pkt,
                           __ATOMIC_RELAXED, __HIP_MEMORY_SCOPE_AGENT);
      if (t < 100) {  // peer packet (proven protocol, unchanged)
        __hip_atomic_store(&hcomm[(t & 1) * EMB + j], pkt,
                           __ATOMIC_RELAXED, __HIP_MEMORY_SCOPE_AGENT);
      }
    }
    if (t < 100) {
      if (tid < EMB && (tid < g * 64 || tid >= g * 64 + 64)) {  // remote slots
        const unsigned long long* slot = &hcomm[(t & 1) * EMB + tid];
        unsigned long long u;
        while (1) {
          u = __hip_atomic_load(slot, __ATOMIC_RELAXED, __HIP_MEMORY_SCOPE_AGENT);
          if ((unsigned)(u >> 32) == (unsigned)(t + 1)) break;
        }
        h_lds[tid] = __uint_as_float((unsigned)u);
      }
      __syncthreads();  // B2: h_lds(t+1) ready
    }
    if (t == 0) {  // switch to W_sum = W_ih + W_hh for steps >= 1
      const float4* whh = (const float4*)(W_hh + R * EMB + half * 128);
#pragma unroll
      for (int q = 0; q < 32; q++) {
        float4 a = whh[q];
        w4[q].x += a.x; w4[q].y += a.y; w4[q].z += a.z; w4[q].w += a.w;
      }
    }
  }
}

// ---------------------------------------------------------------------------
extern "C" void kernel_launch(void* const* d_in, const int* in_sizes, int n_in,
                              void* d_out, int out_size, void* d_ws, size_t ws_size,
                              hipStream_t stream) {
  const float* board  = (const float*)d_in[0];
  const float* conv_w = (const float*)d_in[1];
  const float* conv_b = (const float*)d_in[2];
  const float* bn_g   = (const float*)d_in[3];
  const float* bn_b   = (const float*)d_in[4];
  const float* p      = (const float*)d_in[5];
  const float* W_lin  = (const float*)d_in[6];
  const float* b_lin  = (const float*)d_in[7];
  const float* W_ih   = (const float*)d_in[8];
  const float* b_ih   = (const float*)d_in[9];
  const float* W_hh   = (const float*)d_in[10];
  const float* b_hh   = (const float*)d_in[11];
  const float* W_dec  = (const float*)d_in[12];
  const float* b_dec  = (const float*)d_in[13];

  unsigned long long* hcomm = (unsigned long long*)d_ws;  // 512 u64
  unsigned long long* xtab  = hcomm + 512;                // 32 u64
  unsigned long long* hdec  = xtab + 32;                  // 101*256 u64 history
  unsigned long long* hmir  = hdec + TROWS * EMB;         // 8*2*256 u64 mirrors
  // Total ws: (512+32+25856+4096)*8B ~= 244 KB. No init needed: poison
  // 0xAAAAAAAA never matches tags (hcomm/hdec: t+1 in [1,101]; mirror check
  // requires tag<=101; xtab: 0xE1EC0000).

  k_net<<<NTOT, 512, 0, stream>>>(board, conv_w, conv_b, bn_g, bn_b, p,
                                  W_lin, b_lin, W_ih, b_ih, W_hh, b_hh,
                                  W_dec, b_dec, hcomm, xtab, hdec, hmir,
                                  (float*)d_out);
}

// Round 9
// 370.899 us; speedup vs baseline: 2.8248x; 2.8248x over previous
//
#include <hip/hip_runtime.h>
#include <math.h>

#define EMB 256
#define VOCAB 50000
#define TROWS 101
#define NLB 32    // lstm candidate blocks (election among these; 4 winners)
#define NW 4      // lstm worker workgroups
#define NDECB 196 // decode blocks (196 x 256 vocab rows = 50176 >= 50000)
#define NTOT (NLB + NDECB)

__device__ __forceinline__ float sigf(float x) { return 1.0f / (1.0f + expf(-x)); }

// Opaque register pin: value becomes asm output => compiler cannot
// rematerialize the originating load downstream (rounds 5-8 showed the
// allocator re-streams 128-reg weight arrays from L2/MALL every step:
// 48 MB/step decode, 256 KB/step/WG lstm — the true pipeline pacer).
__device__ __forceinline__ void pin4(float4& v) {
  asm volatile("" : "+v"(v.x), "+v"(v.y), "+v"(v.z), "+v"(v.w));
}

// ---------------------------------------------------------------------------
// K1: conv tower (8 shared-weight conv3x3 + batchnorm stages), single block.
// ---------------------------------------------------------------------------
__global__ __launch_bounds__(384) void k_conv(
    const float* __restrict__ board, const float* __restrict__ conv_w,
    const float* __restrict__ conv_b, const float* __restrict__ bn_g,
    const float* __restrict__ bn_b, const float* __restrict__ p,
    float* __restrict__ d1g) {
  __shared__ float xa[361], xb[361];
  __shared__ float wred[6];
  __shared__ float mu_s, var_s;
  const int tid = threadIdx.x;
  const bool act = tid < 361;
  const int i = tid / 19, j = tid % 19;
  float cw[9];
#pragma unroll
  for (int q = 0; q < 9; q++) cw[q] = conv_w[q];
  const float cb = conv_b[0], gam = bn_g[0], bet = bn_b[0];
  if (act) xa[tid] = board[tid];
  __syncthreads();

  float d2 = 0.f;
  float* cur = xa;
  float* nxt = xb;
  for (int stage = 0; stage < 8; stage++) {
    float y = 0.f;
    if (act) {
#pragma unroll
      for (int di = 0; di < 3; di++) {
#pragma unroll
        for (int dj = 0; dj < 3; dj++) {
          int ii = i + di - 1, jj = j + dj - 1;
          float xv = (ii >= 0 && ii < 19 && jj >= 0 && jj < 19) ? cur[ii * 19 + jj] : 0.f;
          y += cw[di * 3 + dj] * xv;
        }
      }
      y += cb;
    }
    float s = act ? y : 0.f;
#pragma unroll
    for (int o = 32; o > 0; o >>= 1) s += __shfl_xor(s, o);
    if ((tid & 63) == 0) wred[tid >> 6] = s;
    __syncthreads();
    if (tid == 0) {
      float tt = 0.f;
      for (int q = 0; q < 6; q++) tt += wred[q];
      mu_s = tt / 361.f;
    }
    __syncthreads();
    const float mu = mu_s;
    float d = act ? (y - mu) : 0.f;
    s = d * d;
#pragma unroll
    for (int o = 32; o > 0; o >>= 1) s += __shfl_xor(s, o);
    if ((tid & 63) == 0) wred[tid >> 6] = s;
    __syncthreads();
    if (tid == 0) {
      float tt = 0.f;
      for (int q = 0; q < 6; q++) tt += wred[q];
      var_s = tt / 361.f;
    }
    __syncthreads();
    const float xn = gam * (y - mu) * (1.0f / sqrtf(var_s + 1e-5f)) + bet;

    float v;
    if (stage == 0) {
      v = fmaxf(p[0] * xn, 0.f);
      d2 = v;
    } else if (stage == 7) {
      v = fmaxf(xn, 0.f);
    } else if (stage & 1) {
      v = fmaxf(p[stage] * xn, 0.f);
    } else {
      v = fmaxf(p[stage] * xn + d2, 0.f);
      d2 = v;
    }
    if (act) nxt[tid] = v;
    __syncthreads();
    float* tmp = cur; cur = nxt; nxt = tmp;
  }
  if (act) d1g[tid] = cur[tid];
}

// ---------------------------------------------------------------------------
// K2: feat = W_lin @ d1 + b_lin.
// ---------------------------------------------------------------------------
__global__ __launch_bounds__(256) void k_feat(
    const float* __restrict__ W_lin, const float* __restrict__ b_lin,
    const float* __restrict__ d1g, float* __restrict__ feat) {
  const int wid = threadIdx.x >> 6, lane = threadIdx.x & 63;
  const int rbase = blockIdx.x * 16 + wid * 4;
  for (int rr = 0; rr < 4; rr++) {
    const int r = rbase + rr;
    const float* wrow = W_lin + r * 361;
    float s = 0.f;
    for (int k = lane; k < 361; k += 64) s += wrow[k] * d1g[k];
#pragma unroll
    for (int o = 32; o > 0; o >>= 1) s += __shfl_xor(s, o);
    if (lane == 0) feat[r] = s + b_lin[r];
  }
}

// ---------------------------------------------------------------------------
// K3 (fused): LSTM chain + streaming decode — round-5 structure (best
// verified: 415us) + asm-pinned weight registers + waves_per_eu(2,2)
// (cap 256 VGPR so the pinned arrays fit; 8-wave block = 1 block/CU,
// 228 blocks <= 256 CUs, all resident).
// ---------------------------------------------------------------------------
__global__ __launch_bounds__(512)
__attribute__((amdgpu_waves_per_eu(2, 2)))
void k_net(
    const float* __restrict__ W_ih, const float* __restrict__ b_ih,
    const float* __restrict__ W_hh, const float* __restrict__ b_hh,
    const float* __restrict__ feat, const float* __restrict__ W_dec,
    const float* __restrict__ b_dec, unsigned long long* hcomm,
    unsigned long long* xtab, unsigned* hflag, unsigned* hdec,
    float* __restrict__ out) {
  __shared__ float h_lds[EMB];
  __shared__ float gbuf[2][EMB];
  __shared__ float pbuf[2][EMB];
  __shared__ int sxcd[NLB];
  const int tid = threadIdx.x;

  if (blockIdx.x >= NLB) {
    // ======================= decode role =======================
    const int db = blockIdx.x - NLB;          // 0..195
    const int w = tid >> 6, lane = tid & 63;
    const int sh = w & 1;                     // k-half owned: [sh*128, +128)
    const int rr = (w >> 1) * 64 + lane;      // row within tile 0..255
    const int v = db * 256 + rr;
    const int rv = v < VOCAB ? v : VOCAB - 1;
    float4 w4[32];                            // 128 weight cols, PINNED in regs
    {
      const float4* wr = (const float4*)(W_dec + rv * EMB + sh * 128);
#pragma unroll
      for (int q = 0; q < 32; q++) { w4[q] = wr[q]; pin4(w4[q]); }
    }
    const float bd = b_dec[rv];

    for (int t = 0; t < TROWS; t++) {
      if (w == 0) {  // only wave 0 polls the hot flag line
        const unsigned want = (unsigned)(t + 1);
        while (1) {
          const unsigned f0 = __hip_atomic_load(&hflag[t * 4 + 0], __ATOMIC_RELAXED, __HIP_MEMORY_SCOPE_AGENT);
          const unsigned f1 = __hip_atomic_load(&hflag[t * 4 + 1], __ATOMIC_RELAXED, __HIP_MEMORY_SCOPE_AGENT);
          const unsigned f2 = __hip_atomic_load(&hflag[t * 4 + 2], __ATOMIC_RELAXED, __HIP_MEMORY_SCOPE_AGENT);
          const unsigned f3 = __hip_atomic_load(&hflag[t * 4 + 3], __ATOMIC_RELAXED, __HIP_MEMORY_SCOPE_AGENT);
          if (((f0 ^ want) | (f1 ^ want) | (f2 ^ want) | (f3 ^ want)) == 0u) break;
          __builtin_amdgcn_s_sleep(2);
        }
      }
      __syncthreads();  // B1: step-t payloads MALL-visible for all waves

      const float p0 = __uint_as_float(__hip_atomic_load(
          &hdec[t * EMB + sh * 128 + lane], __ATOMIC_RELAXED, __HIP_MEMORY_SCOPE_AGENT));
      const float p1 = __uint_as_float(__hip_atomic_load(
          &hdec[t * EMB + sh * 128 + 64 + lane], __ATOMIC_RELAXED, __HIP_MEMORY_SCOPE_AGENT));

      float a0 = 0.f, a1 = 0.f, a2 = 0.f, a3 = 0.f;
#pragma unroll
      for (int k = 0; k < 32; k++) {
        const float4 wv = w4[k];
        const int kk = 4 * k;
        const float s0 = __uint_as_float(__builtin_amdgcn_readlane(
            __float_as_uint(kk + 0 < 64 ? p0 : p1), (kk + 0) & 63));
        const float s1 = __uint_as_float(__builtin_amdgcn_readlane(
            __float_as_uint(kk + 1 < 64 ? p0 : p1), (kk + 1) & 63));
        const float s2 = __uint_as_float(__builtin_amdgcn_readlane(
            __float_as_uint(kk + 2 < 64 ? p0 : p1), (kk + 2) & 63));
        const float s3 = __uint_as_float(__builtin_amdgcn_readlane(
            __float_as_uint(kk + 3 < 64 ? p0 : p1), (kk + 3) & 63));
        a0 = fmaf(s0, wv.x, a0);
        a1 = fmaf(s1, wv.y, a1);
        a2 = fmaf(s2, wv.z, a2);
        a3 = fmaf(s3, wv.w, a3);
      }
      const float part = (a0 + a1) + (a2 + a3);
      if (sh) pbuf[t & 1][rr] = part;
      __syncthreads();  // B2: partials ready (parity dbuf makes reuse safe)
      if (!sh && v < VOCAB) {
        out[t * VOCAB + v] = fmaxf(part + pbuf[t & 1][rr] + bd, 0.f);
      }
    }
    return;
  }

  // ======================= lstm candidate role =======================
  if (tid == 0) {
    unsigned xcc = __builtin_amdgcn_s_getreg(63508) & 7u;  // HW_REG_XCC_ID
    __hip_atomic_store(&xtab[blockIdx.x],
                       0xE1EC000000000000ULL | (unsigned long long)xcc,
                       __ATOMIC_RELAXED, __HIP_MEMORY_SCOPE_AGENT);
  }
  if (tid < NLB) {
    const unsigned long long* slot = &xtab[tid];
    unsigned long long u;
    while (1) {
      u = __hip_atomic_load(slot, __ATOMIC_RELAXED, __HIP_MEMORY_SCOPE_AGENT);
      if ((unsigned)(u >> 32) == 0xE1EC0000u) break;
      __builtin_amdgcn_s_sleep(2);
    }
    sxcd[tid] = (int)((unsigned)u & 7u);
  }
  __syncthreads();
  int target = -1;
  for (int x = 0; x < 8; x++) {
    int n = 0;
    for (int b = 0; b < NLB; b++) n += (sxcd[b] == x);
    if (n >= NW) { target = x; break; }
  }
  int rank = -1, seen = 0;
  for (int b = 0; b < NLB; b++) {
    if (sxcd[b] == target) {
      if (b == (int)blockIdx.x) rank = seen;
      seen++;
    }
  }
  if (rank < 0 || rank >= NW) return;  // losers exit, free their CUs
  const int g = rank;

  // ---- LSTM body (round-5 proven protocol; weights PINNED) ----
  const int w = tid >> 6, lane = tid & 63;
  const int half = w & 1;
  const int gate = w >> 1;
  const int rloc = gate * 64 + lane;
  const int R = gate * 256 + g * 64 + lane;
  const float bsum = b_ih[R] + b_hh[R];

  float4 w4[32];
  {
    const float4* wih = (const float4*)(W_ih + R * EMB + half * 128);
#pragma unroll
    for (int q = 0; q < 32; q++) { w4[q] = wih[q]; pin4(w4[q]); }
  }
  if (tid < EMB) h_lds[tid] = feat[tid];
  float c = 0.f;
  __syncthreads();

  for (int t = 0; t <= 100; t++) {
    const float hv0 = h_lds[half * 128 + lane];
    const float hv1 = h_lds[half * 128 + 64 + lane];

    float a0 = (half == 0) ? bsum : 0.f, a1 = 0.f, a2 = 0.f, a3 = 0.f;
#pragma unroll
    for (int k = 0; k < 32; k++) {
      const float4 wv = w4[k];
      const int kk = 4 * k;
      const float s0 = __uint_as_float(__builtin_amdgcn_readlane(
          __float_as_uint(kk + 0 < 64 ? hv0 : hv1), (kk + 0) & 63));
      const float s1 = __uint_as_float(__builtin_amdgcn_readlane(
          __float_as_uint(kk + 1 < 64 ? hv0 : hv1), (kk + 1) & 63));
      const float s2 = __uint_as_float(__builtin_amdgcn_readlane(
          __float_as_uint(kk + 2 < 64 ? hv0 : hv1), (kk + 2) & 63));
      const float s3 = __uint_as_float(__builtin_amdgcn_readlane(
          __float_as_uint(kk + 3 < 64 ? hv0 : hv1), (kk + 3) & 63));
      a0 = fmaf(s0, wv.x, a0);
      a1 = fmaf(s1, wv.y, a1);
      a2 = fmaf(s2, wv.z, a2);
      a3 = fmaf(s3, wv.w, a3);
    }
    gbuf[half][rloc] = (a0 + a1) + (a2 + a3);
    __syncthreads();  // B1: gbuf ready; h_lds reads of this step done

    if (tid < 64) {   // producer wave
      const float gi = gbuf[0][tid]       + gbuf[1][tid];
      const float gf = gbuf[0][64 + tid]  + gbuf[1][64 + tid];
      const float gg = gbuf[0][128 + tid] + gbuf[1][128 + tid];
      const float go = gbuf[0][192 + tid] + gbuf[1][192 + tid];
      c = sigf(gf) * c + sigf(gi) * tanhf(gg);
      const float h = sigf(go) * tanhf(c);
      const int j = g * 64 + tid;
      h_lds[j] = h;  // local fast path
      __hip_atomic_store(&hdec[t * EMB + j], __float_as_uint(h),
                         __ATOMIC_RELAXED, __HIP_MEMORY_SCOPE_AGENT);
      if (t < 100) {
        unsigned long long pkt =
            ((unsigned long long)(unsigned)(t + 1) << 32) | (unsigned long long)__float_as_uint(h);
        __hip_atomic_store(&hcomm[(t & 1) * EMB + j], pkt,
                           __ATOMIC_RELAXED, __HIP_MEMORY_SCOPE_AGENT);
      }
      if (tid == 0) {
        // RELEASE: drains this wave's payload stores to the coherence point
        // before the flag lands.
        __hip_atomic_store(&hflag[t * 4 + g], (unsigned)(t + 1),
                           __ATOMIC_RELEASE, __HIP_MEMORY_SCOPE_AGENT);
      }
    }
    if (t < 100) {
      if (tid < EMB && (tid < g * 64 || tid >= g * 64 + 64)) {  // remote slots
        const unsigned long long* slot = &hcomm[(t & 1) * EMB + tid];
        unsigned long long u;
        while (1) {
          u = __hip_atomic_load(slot, __ATOMIC_RELAXED, __HIP_MEMORY_SCOPE_AGENT);
          if ((unsigned)(u >> 32) == (unsigned)(t + 1)) break;
        }
        h_lds[tid] = __uint_as_float((unsigned)u);
      }
      __syncthreads();  // B2: h_lds(t+1) ready
    }
    if (t == 0) {  // switch to W_sum = W_ih + W_hh for steps >= 1; re-pin
      const float4* whh = (const float4*)(W_hh + R * EMB + half * 128);
#pragma unroll
      for (int q = 0; q < 32; q++) {
        float4 a = whh[q];
        w4[q].x += a.x; w4[q].y += a.y; w4[q].z += a.z; w4[q].w += a.w;
        pin4(w4[q]);
      }
    }
  }
}

// ---------------------------------------------------------------------------
extern "C" void kernel_launch(void* const* d_in, const int* in_sizes, int n_in,
                              void* d_out, int out_size, void* d_ws, size_t ws_size,
                              hipStream_t stream) {
  const float* board  = (const float*)d_in[0];
  const float* conv_w = (const float*)d_in[1];
  const float* conv_b = (const float*)d_in[2];
  const float* bn_g   = (const float*)d_in[3];
  const float* bn_b   = (const float*)d_in[4];
  const float* p      = (const float*)d_in[5];
  const float* W_lin  = (const float*)d_in[6];
  const float* b_lin  = (const float*)d_in[7];
  const float* W_ih   = (const float*)d_in[8];
  const float* b_ih   = (const float*)d_in[9];
  const float* W_hh   = (const float*)d_in[10];
  const float* b_hh   = (const float*)d_in[11];
  const float* W_dec  = (const float*)d_in[12];
  const float* b_dec  = (const float*)d_in[13];

  float* wsf = (float*)d_ws;
  float* feat = wsf;                                   // 256 f
  float* d1g  = wsf + 256;                             // 384 f (361 used)
  unsigned long long* hcomm = (unsigned long long*)(wsf + 640);  // 512 u64
  unsigned long long* xtab  = hcomm + 512;             // 32 u64
  unsigned* hflag = (unsigned*)(xtab + 32);            // 512 u32 (404 used)
  unsigned* hdec  = hflag + 512;                       // 101*256 u32
  // No init needed: workspace poison 0xAAAAAAAA never matches the tags
  // (hcomm: t+1 in [1,100]; hflag: t+1 in [1,101]; xtab: 0xE1EC0000).

  k_conv<<<1, 384, 0, stream>>>(board, conv_w, conv_b, bn_g, bn_b, p, d1g);
  k_feat<<<16, 256, 0, stream>>>(W_lin, b_lin, d1g, feat);
  k_net<<<NTOT, 512, 0, stream>>>(W_ih, b_ih, W_hh, b_hh, feat, W_dec, b_dec,
                                  hcomm, xtab, hflag, hdec, (float*)d_out);
}